// Round 5
// baseline (262.744 us; speedup 1.0000x reference)
//
#include <hip/hip_runtime.h>

#define LL 4096
#define HH 1024
#define PP 512
#define RR 16
#define CH 128   // scan chunks
#define CL 32    // steps per chunk

typedef _Float16 f16x8 __attribute__((ext_vector_type(8)));
typedef float f32x16 __attribute__((ext_vector_type(16)));
typedef unsigned short u16;

#define MF32(a, b, c) __builtin_amdgcn_mfma_f32_32x32x16_f16(a, b, c, 0, 0, 0)

__device__ __forceinline__ u16 h16(float x) {
  _Float16 h = (_Float16)x;
  return __builtin_bit_cast(u16, h);
}
__device__ __forceinline__ void splitf(float x, u16& h, u16& l) {
  _Float16 hf = (_Float16)x;
  _Float16 lf = (_Float16)(x - (float)hf);
  h = __builtin_bit_cast(u16, hf);
  l = __builtin_bit_cast(u16, lf);
}

// ---------------------------------------------------------------- precompute
__global__ void precompute_kernel(const float* __restrict__ Lre, const float* __restrict__ Lim,
                                  const float* __restrict__ lst,
                                  const float* __restrict__ Ere, const float* __restrict__ Eim,
                                  const float* __restrict__ Fre, const float* __restrict__ Fim,
                                  float* __restrict__ Lbr, float* __restrict__ Lbi,
                                  float* __restrict__ cfr, float* __restrict__ cfi,
                                  float* __restrict__ EFr, float* __restrict__ EFi)
{
  int p = blockIdx.x * blockDim.x + threadIdx.x;
  if (p >= PP) return;
  float lre = fminf(Lre[p], -1e-4f);   // clip_eigs
  float lim = Lim[p];
  float st  = expf(lst[p]);
  float er  = expf(lre * st);
  float s, c;
  sincosf(lim * st, &s, &c);
  float lbr = er * c, lbi = er * s;    // Lambda_bar
  Lbr[p] = lbr; Lbi[p] = lbi;
  float den = lre * lre + lim * lim;
  float nr  = lbr - 1.0f;
  cfr[p] = (nr * lre + lbi * lim) / den;
  cfi[p] = (lbi * lre - nr * lim) / den;
  for (int r = 0; r < RR; ++r) {
    float e_r = Ere[p * RR + r], e_i = Eim[p * RR + r];
    float f_r = Fre[r * PP + p], f_i = Fim[r * PP + p];
    EFr[r * PP + p] = e_r * f_r - e_i * f_i;
    EFi[r * PP + p] = e_r * f_i + e_i * f_r;
  }
}

// ---------------------------------------------------------------- B_bar -> fp16 planes (re, im)
__global__ void bbar_kernel(const float* __restrict__ Bre, const float* __restrict__ Bim,
                            const float* __restrict__ cfr, const float* __restrict__ cfi,
                            u16* __restrict__ brp, u16* __restrict__ bip)
{
  int i = blockIdx.x * blockDim.x + threadIdx.x;
  int base = i * 4;
  if (base >= PP * HH) return;
  int p = base >> 10;
  float cr = cfr[p], ci = cfi[p];
  float4 br = *(const float4*)&Bre[base];
  float4 bi = *(const float4*)&Bim[base];
  ushort4 rp, ip;
  rp.x = h16(cr*br.x - ci*bi.x); ip.x = h16(cr*bi.x + ci*br.x);
  rp.y = h16(cr*br.y - ci*bi.y); ip.y = h16(cr*bi.y + ci*br.y);
  rp.z = h16(cr*br.z - ci*bi.z); ip.z = h16(cr*bi.z + ci*br.z);
  rp.w = h16(cr*br.w - ci*bi.w); ip.w = h16(cr*bi.w + ci*br.w);
  *(ushort4*)&brp[base] = rp;
  *(ushort4*)&bip[base] = ip;
}

// ---------------------------------------------------------------- u -> fp16 hi/lo
__global__ void split_u_kernel(const float* __restrict__ U,
                               u16* __restrict__ uh, u16* __restrict__ ul)
{
  int i = blockIdx.x * blockDim.x + threadIdx.x;
  int base = i * 4;
  float4 v = *(const float4*)&U[base];
  ushort4 h, l;
  splitf(v.x, h.x, l.x); splitf(v.y, h.y, l.y);
  splitf(v.z, h.z, l.z); splitf(v.w, h.w, l.w);
  *(ushort4*)&uh[base] = h;
  *(ushort4*)&ul[base] = l;
}

// ---------------------------------------------------------------- C -> fp16 planes (Cim negated)
__global__ void convc_kernel(const float* __restrict__ Cre, const float* __restrict__ Cim,
                             u16* __restrict__ crp, u16* __restrict__ cip)
{
  int i = blockIdx.x * blockDim.x + threadIdx.x;
  int base = i * 4;
  float4 a = *(const float4*)&Cre[base];
  float4 b = *(const float4*)&Cim[base];
  ushort4 rp, ip;
  rp.x = h16(a.x); ip.x = h16(-b.x);
  rp.y = h16(a.y); ip.y = h16(-b.y);
  rp.z = h16(a.z); ip.z = h16(-b.z);
  rp.w = h16(a.w); ip.w = h16(-b.w);
  *(ushort4*)&crp[base] = rp;
  *(ushort4*)&cip[base] = ip;
}

// ---------------------------------------------------------------- Lambda elements (fp32)
__global__ __launch_bounds__(256) void lambda_kernel(
    const float* __restrict__ Dt, const float* __restrict__ EFr, const float* __restrict__ EFi,
    const float* __restrict__ Lbr, const float* __restrict__ Lbi,
    float* __restrict__ Ler, float* __restrict__ Lei)
{
  int gid = blockIdx.x * 256 + threadIdx.x;
  int l  = gid >> 7;
  int pq = (gid & 127) << 2;
  float4 ar = *(const float4*)&Lbr[pq];
  float4 ai = *(const float4*)&Lbi[pq];
#pragma unroll
  for (int r = 0; r < RR; ++r) {
    float d = Dt[l * RR + r];
    float4 er = *(const float4*)&EFr[r * PP + pq];
    float4 ei = *(const float4*)&EFi[r * PP + pq];
    ar.x = fmaf(d, er.x, ar.x); ar.y = fmaf(d, er.y, ar.y);
    ar.z = fmaf(d, er.z, ar.z); ar.w = fmaf(d, er.w, ar.w);
    ai.x = fmaf(d, ei.x, ai.x); ai.y = fmaf(d, ei.y, ai.y);
    ai.z = fmaf(d, ei.z, ai.z); ai.w = fmaf(d, ei.w, ai.w);
  }
  *(float4*)&Ler[(size_t)l * PP + pq] = ar;
  *(float4*)&Lei[(size_t)l * PP + pq] = ai;
}

// ---------------------------------------------------------------- gemm1: Bu = u @ B_bar^T
// block 64(L) x 64(P), 4 waves 2x2, wave 32x32, 32x32x16 MFMA, dbuf LDS, grid 512.
// LDS: 16 segs/buf x 1024B; seg = (A: blk*4+ks*2+pl) | (B: 8 + blk*4+ks*2+pl)
// lane l's 16B fragment at (l ^ (seg&7))*16 within segment -> conflict-free reads.
__global__ __launch_bounds__(256) void gemm1_mfma(
    const u16* __restrict__ uh, const u16* __restrict__ ul,
    const u16* __restrict__ brp, const u16* __restrict__ bip,
    float* __restrict__ Bur, float* __restrict__ Bui)
{
  __shared__ uint4 lds[2 * 16 * 64];   // 32 KB
  int g = blockIdx.x;
  int p0 = (g & 7) * 64, l0 = (g >> 3) * 64;
  int t = threadIdx.x;
  int lane = t & 63, w = t >> 6;
  int wr = w >> 1, wc = w & 1;

  // staging decode: thread -> (k8chunk, plane, row)
  int k8 = t & 3, spl = (t >> 2) & 1, srow = t >> 3;   // srow 0..31
  int sks = k8 >> 1, sl32 = (k8 & 1) * 32;
  const u16* gAp = spl ? ul : uh;
  const u16* gBp = spl ? bip : brp;

  uint4 rA[2], rB[2];
  f32x16 accr, acci;
#pragma unroll
  for (int i = 0; i < 16; ++i) { accr[i] = 0.f; acci[i] = 0.f; }

#define G1_LOAD(kt_) do { int kc = (kt_) * 32 + k8 * 8;                        \
    rA[0] = *(const uint4*)&gAp[(size_t)(l0 + srow)      * HH + kc];           \
    rA[1] = *(const uint4*)&gAp[(size_t)(l0 + srow + 32) * HH + kc];           \
    rB[0] = *(const uint4*)&gBp[(size_t)(p0 + srow)      * HH + kc];           \
    rB[1] = *(const uint4*)&gBp[(size_t)(p0 + srow + 32) * HH + kc];           \
  } while (0)
#define G1_WRITE(buf_) do { int bb = (buf_) * 1024;                            \
    _Pragma("unroll") for (int i2 = 0; i2 < 2; ++i2) {                         \
      int seg = i2 * 4 + sks * 2 + spl;                                        \
      lds[bb + seg * 64 + (((srow & 31) + sl32) ^ (seg & 7))] = rA[i2]; }      \
    _Pragma("unroll") for (int i2 = 0; i2 < 2; ++i2) {                         \
      int seg = 8 + i2 * 4 + sks * 2 + spl;                                    \
      lds[bb + seg * 64 + (((srow & 31) + sl32) ^ (seg & 7))] = rB[i2]; }      \
  } while (0)

  G1_LOAD(0); G1_WRITE(0); __syncthreads();
#pragma unroll 2
  for (int kt = 0; kt < HH / 32; ++kt) {
    if (kt + 1 < HH / 32) G1_LOAD(kt + 1);
    int bb = (kt & 1) * 1024;
    f16x8 fa[2][2], fb[2][2];
#pragma unroll
    for (int ks = 0; ks < 2; ++ks)
#pragma unroll
      for (int pl = 0; pl < 2; ++pl) {
        int segA = wr * 4 + ks * 2 + pl;
        int segB = 8 + wc * 4 + ks * 2 + pl;
        fa[ks][pl] = *(const f16x8*)&lds[bb + segA * 64 + (lane ^ (segA & 7))];
        fb[ks][pl] = *(const f16x8*)&lds[bb + segB * 64 + (lane ^ (segB & 7))];
      }
#pragma unroll
    for (int ks = 0; ks < 2; ++ks) {
      accr = MF32(fa[ks][0], fb[ks][0], accr);
      accr = MF32(fa[ks][1], fb[ks][0], accr);
      acci = MF32(fa[ks][0], fb[ks][1], acci);
      acci = MF32(fa[ks][1], fb[ks][1], acci);
    }
    if (kt + 1 < HH / 32) G1_WRITE((kt + 1) & 1);
    __syncthreads();
  }

  // direct stores: per reg j, 32 lanes cover 32 consecutive p (128B segments)
  int col = p0 + wc * 32 + (lane & 31);
  int rowb = l0 + wr * 32 + 4 * (lane >> 5);
#pragma unroll
  for (int j = 0; j < 16; ++j) {
    int row = rowb + (j & 3) + 8 * (j >> 2);
    size_t idx = (size_t)row * PP + col;
    Bur[idx] = accr[j];
    Bui[idx] = acci[j];
  }
}

// ---------------------------------------------------------------- scan phase 1
__global__ __launch_bounds__(256) void scan_agg_kernel(
    const float* __restrict__ Aer, const float* __restrict__ Aei,
    const float* __restrict__ Bur, const float* __restrict__ Bui,
    float* __restrict__ aggAr, float* __restrict__ aggAi,
    float* __restrict__ aggBr, float* __restrict__ aggBi)
{
  int tid = blockIdx.x * 256 + threadIdx.x;
  int p   = tid & (PP - 1);
  int c   = (tid >> 9) & (CH - 1);
  int dir = tid >> 16;
  float Ar = 1.f, Ai = 0.f, br = 0.f, bi = 0.f;
  int base = c * CL;
#pragma unroll
  for (int g = 0; g < CL / 8; ++g) {
    float ar8[8], ai8[8], br8[8], bi8[8];
#pragma unroll
    for (int u = 0; u < 8; ++u) {
      int l = base + g * 8 + u;
      int phys = dir ? (LL - 1 - l) : l;
      int idx = phys * PP + p;
      ar8[u] = Aer[idx]; ai8[u] = Aei[idx];
      br8[u] = Bur[idx]; bi8[u] = Bui[idx];
    }
#pragma unroll
    for (int u = 0; u < 8; ++u) {
      float nAr = ar8[u] * Ar - ai8[u] * Ai;
      float nAi = ar8[u] * Ai + ai8[u] * Ar;
      float nbr = fmaf(ar8[u], br, fmaf(-ai8[u], bi, br8[u]));
      float nbi = fmaf(ar8[u], bi, fmaf( ai8[u], br, bi8[u]));
      Ar = nAr; Ai = nAi; br = nbr; bi = nbi;
    }
  }
  aggAr[tid] = Ar; aggAi[tid] = Ai; aggBr[tid] = br; aggBi[tid] = bi;
}

// ---------------------------------------------------------------- scan phase 2
__global__ __launch_bounds__(256) void scan_carry_kernel(
    const float* __restrict__ aggAr, const float* __restrict__ aggAi,
    const float* __restrict__ aggBr, const float* __restrict__ aggBi,
    float* __restrict__ carR, float* __restrict__ carI)
{
  int tid = blockIdx.x * 256 + threadIdx.x;
  int p   = tid & (PP - 1);
  int dir = tid >> 9;
  float xr = 0.f, xi = 0.f;
  for (int c = 0; c < CH; ++c) {
    int idx = (dir * CH + c) * PP + p;
    carR[idx] = xr; carI[idx] = xi;
    float ar = aggAr[idx], ai = aggAi[idx];
    float br = aggBr[idx], bi = aggBi[idx];
    float nr = fmaf(ar, xr, fmaf(-ai, xi, br));
    float ni = fmaf(ar, xi, fmaf( ai, xr, bi));
    xr = nr; xi = ni;
  }
}

// ---------------------------------------------------------------- scan phase 3 (writes fp16 planes)
__global__ __launch_bounds__(256) void scan_apply_kernel(
    const float* __restrict__ Aer, const float* __restrict__ Aei,
    const float* __restrict__ Bur, const float* __restrict__ Bui,
    const float* __restrict__ carR, const float* __restrict__ carI,
    u16* __restrict__ xrp, u16* __restrict__ xip)
{
  int tid = blockIdx.x * 256 + threadIdx.x;
  int p   = tid & (PP - 1);
  int c   = (tid >> 9) & (CH - 1);
  int dir = tid >> 16;
  float xr = carR[tid], xi = carI[tid];
  int base = c * CL;
  int cofs = dir * PP + p;      // column in merged [L][2P] planes
#pragma unroll
  for (int g = 0; g < CL / 8; ++g) {
    float ar8[8], ai8[8], br8[8], bi8[8];
#pragma unroll
    for (int u = 0; u < 8; ++u) {
      int l = base + g * 8 + u;
      int phys = dir ? (LL - 1 - l) : l;
      int idx = phys * PP + p;
      ar8[u] = Aer[idx]; ai8[u] = Aei[idx];
      br8[u] = Bur[idx]; bi8[u] = Bui[idx];
    }
#pragma unroll
    for (int u = 0; u < 8; ++u) {
      float nr = fmaf(ar8[u], xr, fmaf(-ai8[u], xi, br8[u]));
      float ni = fmaf(ar8[u], xi, fmaf( ai8[u], xr, bi8[u]));
      xr = nr; xi = ni;
      int l = base + g * 8 + u;
      int phys = dir ? (LL - 1 - l) : l;
      size_t col = (size_t)phys * (2 * PP) + cofs;
      xrp[col] = h16(xr);
      xip[col] = h16(xi);
    }
  }
}

// ---------------------------------------------------------------- gemm2: Y = 2*Re(xs @ C^T) + D*u
// block 64(L) x 128(H), 4 waves 2x2, wave 32x64, 32x32x16 MFMA, dbuf LDS, grid 512.
// A = xs planes [L][1024], B = C planes [H][1024] (cip pre-negated).
__global__ __launch_bounds__(256) void gemm2_mfma(
    const u16* __restrict__ xrp, const u16* __restrict__ xip,
    const u16* __restrict__ crp, const u16* __restrict__ cip,
    const float* __restrict__ Dv, const float* __restrict__ U,
    float* __restrict__ Y)
{
  __shared__ uint4 lds[2 * 24 * 64];   // 48 KB
  int g = blockIdx.x;
  int h0 = (g & 7) * 128, l0 = (g >> 3) * 64;
  int t = threadIdx.x;
  int lane = t & 63, w = t >> 6;
  int wr = w >> 1, wc = w & 1;

  int k8 = t & 3, spl = (t >> 2) & 1, srow = t >> 3;   // srow 0..31
  int sks = k8 >> 1, sl32 = (k8 & 1) * 32;
  const u16* gAp = spl ? xip : xrp;
  const u16* gBp = spl ? cip : crp;

  uint4 rA[2], rB[4];
  f32x16 acc[2];
#pragma unroll
  for (int n = 0; n < 2; ++n)
#pragma unroll
    for (int i = 0; i < 16; ++i) acc[n][i] = 0.f;

#define G2_LOAD(kt_) do { int kc = (kt_) * 32 + k8 * 8;                        \
    rA[0] = *(const uint4*)&gAp[(size_t)(l0 + srow)      * 1024 + kc];         \
    rA[1] = *(const uint4*)&gAp[(size_t)(l0 + srow + 32) * 1024 + kc];         \
    _Pragma("unroll") for (int i2 = 0; i2 < 4; ++i2)                           \
      rB[i2] = *(const uint4*)&gBp[(size_t)(h0 + srow + 32 * i2) * 1024 + kc]; \
  } while (0)
#define G2_WRITE(buf_) do { int bb = (buf_) * 1536;                            \
    _Pragma("unroll") for (int i2 = 0; i2 < 2; ++i2) {                         \
      int seg = i2 * 4 + sks * 2 + spl;                                        \
      lds[bb + seg * 64 + (((srow & 31) + sl32) ^ (seg & 7))] = rA[i2]; }      \
    _Pragma("unroll") for (int i2 = 0; i2 < 4; ++i2) {                         \
      int seg = 8 + i2 * 4 + sks * 2 + spl;                                    \
      lds[bb + seg * 64 + (((srow & 31) + sl32) ^ (seg & 7))] = rB[i2]; }      \
  } while (0)

  G2_LOAD(0); G2_WRITE(0); __syncthreads();
#pragma unroll 2
  for (int kt = 0; kt < 32; ++kt) {
    if (kt + 1 < 32) G2_LOAD(kt + 1);
    int bb = (kt & 1) * 1536;
    f16x8 fa[2][2], fb[2][2][2];
#pragma unroll
    for (int ks = 0; ks < 2; ++ks)
#pragma unroll
      for (int pl = 0; pl < 2; ++pl) {
        int segA = wr * 4 + ks * 2 + pl;
        fa[ks][pl] = *(const f16x8*)&lds[bb + segA * 64 + (lane ^ (segA & 7))];
#pragma unroll
        for (int nf = 0; nf < 2; ++nf) {
          int segB = 8 + (wc * 2 + nf) * 4 + ks * 2 + pl;
          fb[ks][nf][pl] = *(const f16x8*)&lds[bb + segB * 64 + (lane ^ (segB & 7))];
        }
      }
#pragma unroll
    for (int ks = 0; ks < 2; ++ks)
#pragma unroll
      for (int nf = 0; nf < 2; ++nf) {
        acc[nf] = MF32(fa[ks][0], fb[ks][nf][0], acc[nf]);
        acc[nf] = MF32(fa[ks][1], fb[ks][nf][1], acc[nf]);
      }
    if (kt + 1 < 32) G2_WRITE((kt + 1) & 1);
    __syncthreads();
  }

  // direct stores, fused 2x + D*u
  int colb = h0 + wc * 64 + (lane & 31);
  int rowb = l0 + wr * 32 + 4 * (lane >> 5);
#pragma unroll
  for (int nf = 0; nf < 2; ++nf) {
    int col = colb + nf * 32;
    float dv = Dv[col];
#pragma unroll
    for (int j = 0; j < 16; ++j) {
      int row = rowb + (j & 3) + 8 * (j >> 2);
      size_t idx = (size_t)row * HH + col;
      Y[idx] = 2.0f * acc[nf][j] + dv * U[idx];
    }
  }
}

// ---------------------------------------------------------------- launch
extern "C" void kernel_launch(void* const* d_in, const int* in_sizes, int n_in,
                              void* d_out, int out_size, void* d_ws, size_t ws_size,
                              hipStream_t stream)
{
  const float* U   = (const float*)d_in[0];
  const float* Lre = (const float*)d_in[1];
  const float* Lim = (const float*)d_in[2];
  const float* Bre = (const float*)d_in[3];
  const float* Bim = (const float*)d_in[4];
  const float* Cre = (const float*)d_in[5];
  const float* Cim = (const float*)d_in[6];
  const float* Ere = (const float*)d_in[7];
  const float* Eim = (const float*)d_in[8];
  const float* Fre = (const float*)d_in[9];
  const float* Fim = (const float*)d_in[10];
  const float* Dv  = (const float*)d_in[11];
  const float* lst = (const float*)d_in[12];
  const float* Dt  = (const float*)d_in[13];
  float* Y = (float*)d_out;

  char* wsb = (char*)d_ws;
  size_t o = 0;
  auto alloc = [&](size_t bytes) -> char* {
    char* r = wsb + o; o += (bytes + 255) & ~(size_t)255; return r;
  };
  float* Lbr = (float*)alloc(PP * 4);
  float* Lbi = (float*)alloc(PP * 4);
  float* cfr = (float*)alloc(PP * 4);
  float* cfi = (float*)alloc(PP * 4);
  float* EFr = (float*)alloc((size_t)RR * PP * 4);
  float* EFi = (float*)alloc((size_t)RR * PP * 4);
  u16* uh  = (u16*)alloc((size_t)LL * HH * 2);
  u16* ul  = (u16*)alloc((size_t)LL * HH * 2);
  u16* brp = (u16*)alloc((size_t)PP * HH * 2);
  u16* bip = (u16*)alloc((size_t)PP * HH * 2);
  float* Ler = (float*)alloc((size_t)LL * PP * 4);
  float* Lei = (float*)alloc((size_t)LL * PP * 4);
  float* Bur = (float*)alloc((size_t)LL * PP * 4);
  float* Bui = (float*)alloc((size_t)LL * PP * 4);
  u16* xrp = (u16*)alloc((size_t)LL * 2 * PP * 2);
  u16* xip = (u16*)alloc((size_t)LL * 2 * PP * 2);
  u16* crp = (u16*)alloc((size_t)HH * 2 * PP * 2);
  u16* cip = (u16*)alloc((size_t)HH * 2 * PP * 2);
  const int NAGG = 2 * CH * PP;       // 131072
  float* aggAr = (float*)alloc((size_t)NAGG * 4);
  float* aggAi = (float*)alloc((size_t)NAGG * 4);
  float* aggBr = (float*)alloc((size_t)NAGG * 4);
  float* aggBi = (float*)alloc((size_t)NAGG * 4);
  float* carR  = (float*)alloc((size_t)NAGG * 4);
  float* carI  = (float*)alloc((size_t)NAGG * 4);

  precompute_kernel<<<2, 256, 0, stream>>>(Lre, Lim, lst, Ere, Eim, Fre, Fim,
                                           Lbr, Lbi, cfr, cfi, EFr, EFi);
  bbar_kernel<<<PP * HH / 4 / 256, 256, 0, stream>>>(Bre, Bim, cfr, cfi, brp, bip);
  split_u_kernel<<<LL * HH / 4 / 256, 256, 0, stream>>>(U, uh, ul);
  lambda_kernel<<<LL * PP / 4 / 256, 256, 0, stream>>>(Dt, EFr, EFi, Lbr, Lbi, Ler, Lei);
  convc_kernel<<<HH * 2 * PP / 4 / 256, 256, 0, stream>>>(Cre, Cim, crp, cip);
  gemm1_mfma<<<512, 256, 0, stream>>>(uh, ul, brp, bip, Bur, Bui);
  scan_agg_kernel<<<2 * CH * PP / 256, 256, 0, stream>>>(Ler, Lei, Bur, Bui,
                                                         aggAr, aggAi, aggBr, aggBi);
  scan_carry_kernel<<<4, 256, 0, stream>>>(aggAr, aggAi, aggBr, aggBi, carR, carI);
  scan_apply_kernel<<<2 * CH * PP / 256, 256, 0, stream>>>(Ler, Lei, Bur, Bui, carR, carI,
                                                           xrp, xip);
  gemm2_mfma<<<512, 256, 0, stream>>>(xrp, xip, crp, cip, Dv, U, Y);
}

// Round 7
// 134.920 us; speedup vs baseline: 1.9474x; 1.9474x over previous
//
#include <hip/hip_runtime.h>

#define LL 4096
#define HH 1024
#define PP 512
#define RR 16
#define CH 128   // scan chunks
#define CL 32    // steps per chunk

typedef _Float16 f16x8 __attribute__((ext_vector_type(8)));
typedef float f32x4 __attribute__((ext_vector_type(4)));
typedef unsigned short u16;
typedef unsigned int u32;

#define MF16(a, b, c) __builtin_amdgcn_mfma_f32_16x16x32_f16(a, b, c, 0, 0, 0)

__device__ __forceinline__ u16 h16(float x) {
  _Float16 h = (_Float16)x;
  return __builtin_bit_cast(u16, h);
}

// ---------------------------------------------------------------- precompute
__global__ void precompute_kernel(const float* __restrict__ Lre, const float* __restrict__ Lim,
                                  const float* __restrict__ lst,
                                  const float* __restrict__ Ere, const float* __restrict__ Eim,
                                  const float* __restrict__ Fre, const float* __restrict__ Fim,
                                  float* __restrict__ Lbr, float* __restrict__ Lbi,
                                  float* __restrict__ cfr, float* __restrict__ cfi,
                                  float* __restrict__ EFr, float* __restrict__ EFi)
{
  int p = blockIdx.x * blockDim.x + threadIdx.x;
  if (p >= PP) return;
  float lre = fminf(Lre[p], -1e-4f);   // clip_eigs
  float lim = Lim[p];
  float st  = expf(lst[p]);
  float er  = expf(lre * st);
  float s, c;
  sincosf(lim * st, &s, &c);
  float lbr = er * c, lbi = er * s;    // Lambda_bar
  Lbr[p] = lbr; Lbi[p] = lbi;
  float den = lre * lre + lim * lim;
  float nr  = lbr - 1.0f;
  cfr[p] = (nr * lre + lbi * lim) / den;
  cfi[p] = (lbi * lre - nr * lim) / den;
  for (int r = 0; r < RR; ++r) {
    float e_r = Ere[p * RR + r], e_i = Eim[p * RR + r];
    float f_r = Fre[r * PP + p], f_i = Fim[r * PP + p];
    EFr[r * PP + p] = e_r * f_r - e_i * f_i;
    EFi[r * PP + p] = e_r * f_i + e_i * f_r;
  }
}

// ---------------------------------------------------------------- B_bar -> B1 fp16 [1024][1024]
// rows p: re(B_bar), rows 512+p: im(B_bar)
__global__ void bbar_kernel(const float* __restrict__ Bre, const float* __restrict__ Bim,
                            const float* __restrict__ cfr, const float* __restrict__ cfi,
                            u16* __restrict__ B1)
{
  int i = blockIdx.x * blockDim.x + threadIdx.x;
  int base = i * 4;
  if (base >= PP * HH) return;
  int p = base >> 10, col = base & 1023;
  float cr = cfr[p], ci = cfi[p];
  float4 br = *(const float4*)&Bre[base];
  float4 bi = *(const float4*)&Bim[base];
  ushort4 rp, ip;
  rp.x = h16(cr*br.x - ci*bi.x); ip.x = h16(cr*bi.x + ci*br.x);
  rp.y = h16(cr*br.y - ci*bi.y); ip.y = h16(cr*bi.y + ci*br.y);
  rp.z = h16(cr*br.z - ci*bi.z); ip.z = h16(cr*bi.z + ci*br.z);
  rp.w = h16(cr*br.w - ci*bi.w); ip.w = h16(cr*bi.w + ci*br.w);
  *(ushort4*)&B1[(size_t)p * 1024 + col] = rp;
  *(ushort4*)&B1[(size_t)(PP + p) * 1024 + col] = ip;
}

// ---------------------------------------------------------------- C -> B2 interleaved (cr,-ci) [1024][2048]
__global__ void prep_c_kernel(const float* __restrict__ Cre, const float* __restrict__ Cim,
                              u32* __restrict__ B2)
{
  int i = blockIdx.x * blockDim.x + threadIdx.x;
  int base = i * 4;                       // k index in [0,1024)
  float4 a = *(const float4*)&Cre[base];
  float4 b = *(const float4*)&Cim[base];
  uint4 o;
  o.x = (u32)h16(a.x) | ((u32)h16(-b.x) << 16);
  o.y = (u32)h16(a.y) | ((u32)h16(-b.y) << 16);
  o.z = (u32)h16(a.z) | ((u32)h16(-b.z) << 16);
  o.w = (u32)h16(a.w) | ((u32)h16(-b.w) << 16);
  *(uint4*)&B2[base] = o;
}

// ---------------------------------------------------------------- Lambda elements (fp32)
__global__ __launch_bounds__(256) void lambda_kernel(
    const float* __restrict__ Dt, const float* __restrict__ EFr, const float* __restrict__ EFi,
    const float* __restrict__ Lbr, const float* __restrict__ Lbi,
    float* __restrict__ Ler, float* __restrict__ Lei)
{
  int gid = blockIdx.x * 256 + threadIdx.x;
  int l  = gid >> 7;
  int pq = (gid & 127) << 2;
  float4 ar = *(const float4*)&Lbr[pq];
  float4 ai = *(const float4*)&Lbi[pq];
#pragma unroll
  for (int r = 0; r < RR; ++r) {
    float d = Dt[l * RR + r];
    float4 er = *(const float4*)&EFr[r * PP + pq];
    float4 ei = *(const float4*)&EFi[r * PP + pq];
    ar.x = fmaf(d, er.x, ar.x); ar.y = fmaf(d, er.y, ar.y);
    ar.z = fmaf(d, er.z, ar.z); ar.w = fmaf(d, er.w, ar.w);
    ai.x = fmaf(d, ei.x, ai.x); ai.y = fmaf(d, ei.y, ai.y);
    ai.z = fmaf(d, ei.z, ai.z); ai.w = fmaf(d, ei.w, ai.w);
  }
  *(float4*)&Ler[(size_t)l * PP + pq] = ar;
  *(float4*)&Lei[(size_t)l * PP + pq] = ai;
}

// ---------------------------------------------------------------- unified GEMM
// out[M][1024] = A[M][Kp] @ B[1024][Kp]^T, fp16 operands, fp32 acc.
// 64x64 block tile, 4 waves 2x2 (32x32 each), 16x16x32 MFMA, BK=32.
// grid = 16 n-tiles * (M/64); n-tile = (bid&7)*2 + ((bid>>3)&1) -> XCD-resident B panel.
// 2-deep global prefetch; LDS rows padded to 40 shorts (uniform bank spread).
// EPI 0: plain store. EPI 1: out = 2*acc + Dv*Uep. ACVT: A is fp32, convert in staging.
template<int EPI, bool ACVT>
__global__ __launch_bounds__(256) void gemm_k(
    const void* __restrict__ Asrc, const u16* __restrict__ Bsrc, int Kp,
    float* __restrict__ out, const float* __restrict__ Dv,
    const float* __restrict__ Uep)
{
  __shared__ __align__(16) u16 smem[2 * 2 * 64 * 40];   // [buf][op][row][40] = 20.5 KB
  int bid = blockIdx.x;
  int n0 = ((bid & 7) * 2 + ((bid >> 3) & 1)) * 64;
  int m0 = (bid >> 4) * 64;
  int t = threadIdx.x, lane = t & 63, w = t >> 6;
  int wr = w >> 1, wc = w & 1;
  int rl = lane & 15, kg = lane >> 4;
  int crow = t >> 2, cch = t & 3;
  int NT = Kp / 32;

  const float* Af = (const float*)Asrc;
  const u16*   Ah = (const u16*)Asrc;

  f32x4 acc[2][2];
  acc[0][0] = acc[0][1] = acc[1][0] = acc[1][1] = (f32x4){0.f, 0.f, 0.f, 0.f};

  auto LOADA = [&](int kt) -> f16x8 {
    if constexpr (ACVT) {
      const float* p = Af + (size_t)(m0 + crow) * Kp + kt * 32 + cch * 8;
      float4 a = *(const float4*)p, b = *(const float4*)(p + 4);
      f16x8 r;
      r[0] = (_Float16)a.x; r[1] = (_Float16)a.y; r[2] = (_Float16)a.z; r[3] = (_Float16)a.w;
      r[4] = (_Float16)b.x; r[5] = (_Float16)b.y; r[6] = (_Float16)b.z; r[7] = (_Float16)b.w;
      return r;
    } else {
      return *(const f16x8*)(Ah + (size_t)(m0 + crow) * Kp + kt * 32 + cch * 8);
    }
  };
  auto LOADB = [&](int kt) -> f16x8 {
    return *(const f16x8*)(Bsrc + (size_t)(n0 + crow) * Kp + kt * 32 + cch * 8);
  };
  auto WRITE = [&](int buf, f16x8 ra, f16x8 rb) {
    *(f16x8*)&smem[((buf * 2 + 0) * 64 + crow) * 40 + cch * 8] = ra;
    *(f16x8*)&smem[((buf * 2 + 1) * 64 + crow) * 40 + cch * 8] = rb;
  };

  f16x8 rAn, rBn, rAf = {}, rBf = {};
  WRITE(0, LOADA(0), LOADB(0));
  rAn = LOADA(1); rBn = LOADB(1);
  __syncthreads();

#pragma unroll 2
  for (int kt = 0; kt < NT; ++kt) {
    int c = kt & 1;
    if (kt + 2 < NT) { rAf = LOADA(kt + 2); rBf = LOADB(kt + 2); }
    f16x8 af[2], bf[2];
#pragma unroll
    for (int m = 0; m < 2; ++m)
      af[m] = *(const f16x8*)&smem[((c * 2 + 0) * 64 + wr * 32 + m * 16 + rl) * 40 + kg * 8];
#pragma unroll
    for (int n = 0; n < 2; ++n)
      bf[n] = *(const f16x8*)&smem[((c * 2 + 1) * 64 + wc * 32 + n * 16 + rl) * 40 + kg * 8];
#pragma unroll
    for (int m = 0; m < 2; ++m)
#pragma unroll
      for (int n = 0; n < 2; ++n)
        acc[m][n] = MF16(af[m], bf[n], acc[m][n]);
    if (kt + 1 < NT) WRITE(c ^ 1, rAn, rBn);
    rAn = rAf; rBn = rBf;
    __syncthreads();
  }

  // epilogue: stage in LDS (reuse smem), float4 stores
  float* Stg = (float*)smem;   // [64][68]
#pragma unroll
  for (int m = 0; m < 2; ++m)
#pragma unroll
    for (int n = 0; n < 2; ++n)
#pragma unroll
      for (int j = 0; j < 4; ++j)
        Stg[(wr * 32 + m * 16 + kg * 4 + j) * 68 + wc * 32 + n * 16 + rl] = acc[m][n][j];
  __syncthreads();
  int col4 = (t & 15) * 4, prow = t >> 4;
#pragma unroll
  for (int i = 0; i < 4; ++i) {
    int r = prow + 16 * i;
    float4 v = *(const float4*)&Stg[r * 68 + col4];
    size_t ob = (size_t)(m0 + r) * 1024 + n0 + col4;
    if constexpr (EPI == 1) {
      float4 u4 = *(const float4*)&Uep[ob];
      float4 dv = *(const float4*)&Dv[n0 + col4];
      v.x = 2.f * v.x + dv.x * u4.x; v.y = 2.f * v.y + dv.y * u4.y;
      v.z = 2.f * v.z + dv.z * u4.z; v.w = 2.f * v.w + dv.w * u4.w;
    }
    *(float4*)&out[ob] = v;
  }
}

// ---------------------------------------------------------------- scan phase 1
// Bu columns live in P: re at P[l][p], im at P[l][512+p]
__global__ __launch_bounds__(256) void scan_agg_kernel(
    const float* __restrict__ Aer, const float* __restrict__ Aei,
    const float* __restrict__ P,
    float* __restrict__ aggAr, float* __restrict__ aggAi,
    float* __restrict__ aggBr, float* __restrict__ aggBi)
{
  int tid = blockIdx.x * 256 + threadIdx.x;
  int p   = tid & (PP - 1);
  int c   = (tid >> 9) & (CH - 1);
  int dir = tid >> 16;
  float Ar = 1.f, Ai = 0.f, br = 0.f, bi = 0.f;
  int base = c * CL;
#pragma unroll
  for (int g = 0; g < CL / 8; ++g) {
    float ar8[8], ai8[8], br8[8], bi8[8];
#pragma unroll
    for (int u = 0; u < 8; ++u) {
      int l = base + g * 8 + u;
      int phys = dir ? (LL - 1 - l) : l;
      ar8[u] = Aer[phys * PP + p]; ai8[u] = Aei[phys * PP + p];
      br8[u] = P[(size_t)phys * 1024 + p];
      bi8[u] = P[(size_t)phys * 1024 + PP + p];
    }
#pragma unroll
    for (int u = 0; u < 8; ++u) {
      float nAr = ar8[u] * Ar - ai8[u] * Ai;
      float nAi = ar8[u] * Ai + ai8[u] * Ar;
      float nbr = fmaf(ar8[u], br, fmaf(-ai8[u], bi, br8[u]));
      float nbi = fmaf(ar8[u], bi, fmaf( ai8[u], br, bi8[u]));
      Ar = nAr; Ai = nAi; br = nbr; bi = nbi;
    }
  }
  aggAr[tid] = Ar; aggAi[tid] = Ai; aggBr[tid] = br; aggBi[tid] = bi;
}

// ---------------------------------------------------------------- scan phase 2
__global__ __launch_bounds__(256) void scan_carry_kernel(
    const float* __restrict__ aggAr, const float* __restrict__ aggAi,
    const float* __restrict__ aggBr, const float* __restrict__ aggBi,
    float* __restrict__ carR, float* __restrict__ carI)
{
  int tid = blockIdx.x * 256 + threadIdx.x;
  int p   = tid & (PP - 1);
  int dir = tid >> 9;
  float xr = 0.f, xi = 0.f;
  for (int c = 0; c < CH; ++c) {
    int idx = (dir * CH + c) * PP + p;
    carR[idx] = xr; carI[idx] = xi;
    float ar = aggAr[idx], ai = aggAi[idx];
    float br = aggBr[idx], bi = aggBi[idx];
    float nr = fmaf(ar, xr, fmaf(-ai, xi, br));
    float ni = fmaf(ar, xi, fmaf( ai, xr, bi));
    xr = nr; xi = ni;
  }
}

// ---------------------------------------------------------------- scan phase 3
// writes A2[l][k] = (h16(im)<<16)|h16(re), k = dir*512+p  (interleaved fp16 pairs)
__global__ __launch_bounds__(256) void scan_apply_kernel(
    const float* __restrict__ Aer, const float* __restrict__ Aei,
    const float* __restrict__ P,
    const float* __restrict__ carR, const float* __restrict__ carI,
    u32* __restrict__ A2)
{
  int tid = blockIdx.x * 256 + threadIdx.x;
  int p   = tid & (PP - 1);
  int c   = (tid >> 9) & (CH - 1);
  int dir = tid >> 16;
  float xr = carR[tid], xi = carI[tid];
  int base = c * CL;
  int cofs = dir * PP + p;
#pragma unroll
  for (int g = 0; g < CL / 8; ++g) {
    float ar8[8], ai8[8], br8[8], bi8[8];
#pragma unroll
    for (int u = 0; u < 8; ++u) {
      int l = base + g * 8 + u;
      int phys = dir ? (LL - 1 - l) : l;
      ar8[u] = Aer[phys * PP + p]; ai8[u] = Aei[phys * PP + p];
      br8[u] = P[(size_t)phys * 1024 + p];
      bi8[u] = P[(size_t)phys * 1024 + PP + p];
    }
#pragma unroll
    for (int u = 0; u < 8; ++u) {
      float nr = fmaf(ar8[u], xr, fmaf(-ai8[u], xi, br8[u]));
      float ni = fmaf(ar8[u], xi, fmaf( ai8[u], xr, bi8[u]));
      xr = nr; xi = ni;
      int l = base + g * 8 + u;
      int phys = dir ? (LL - 1 - l) : l;
      A2[(size_t)phys * 1024 + cofs] = (u32)h16(xr) | ((u32)h16(xi) << 16);
    }
  }
}

// ---------------------------------------------------------------- launch
extern "C" void kernel_launch(void* const* d_in, const int* in_sizes, int n_in,
                              void* d_out, int out_size, void* d_ws, size_t ws_size,
                              hipStream_t stream)
{
  const float* U   = (const float*)d_in[0];
  const float* Lre = (const float*)d_in[1];
  const float* Lim = (const float*)d_in[2];
  const float* Bre = (const float*)d_in[3];
  const float* Bim = (const float*)d_in[4];
  const float* Cre = (const float*)d_in[5];
  const float* Cim = (const float*)d_in[6];
  const float* Ere = (const float*)d_in[7];
  const float* Eim = (const float*)d_in[8];
  const float* Fre = (const float*)d_in[9];
  const float* Fim = (const float*)d_in[10];
  const float* Dv  = (const float*)d_in[11];
  const float* lst = (const float*)d_in[12];
  const float* Dt  = (const float*)d_in[13];
  float* Y = (float*)d_out;

  char* wsb = (char*)d_ws;
  size_t o = 0;
  auto alloc = [&](size_t bytes) -> char* {
    char* r = wsb + o; o += (bytes + 255) & ~(size_t)255; return r;
  };
  float* Lbr = (float*)alloc(PP * 4);
  float* Lbi = (float*)alloc(PP * 4);
  float* cfr = (float*)alloc(PP * 4);
  float* cfi = (float*)alloc(PP * 4);
  float* EFr = (float*)alloc((size_t)RR * PP * 4);
  float* EFi = (float*)alloc((size_t)RR * PP * 4);
  u16* B1 = (u16*)alloc((size_t)1024 * 1024 * 2);        // [p|512+p][k] = re|im B_bar
  u32* B2 = (u32*)alloc((size_t)1024 * 1024 * 4);        // C interleaved (cr,-ci)
  float* Ler = (float*)alloc((size_t)LL * PP * 4);
  float* Lei = (float*)alloc((size_t)LL * PP * 4);
  float* P   = (float*)alloc((size_t)LL * 1024 * 4);     // [Bur | Bui]
  u32* A2 = (u32*)alloc((size_t)LL * 1024 * 4);          // xs interleaved
  const int NAGG = 2 * CH * PP;                          // 131072
  float* aggAr = (float*)alloc((size_t)NAGG * 4);
  float* aggAi = (float*)alloc((size_t)NAGG * 4);
  float* aggBr = (float*)alloc((size_t)NAGG * 4);
  float* aggBi = (float*)alloc((size_t)NAGG * 4);
  float* carR  = (float*)alloc((size_t)NAGG * 4);
  float* carI  = (float*)alloc((size_t)NAGG * 4);

  precompute_kernel<<<2, 256, 0, stream>>>(Lre, Lim, lst, Ere, Eim, Fre, Fim,
                                           Lbr, Lbi, cfr, cfi, EFr, EFi);
  bbar_kernel<<<PP * HH / 4 / 256, 256, 0, stream>>>(Bre, Bim, cfr, cfi, B1);
  prep_c_kernel<<<1024 * 1024 / 4 / 256, 256, 0, stream>>>(Cre, Cim, B2);
  lambda_kernel<<<LL * PP / 4 / 256, 256, 0, stream>>>(Dt, EFr, EFi, Lbr, Lbi, Ler, Lei);
  gemm_k<0, true><<<1024, 256, 0, stream>>>(U, B1, 1024, P, nullptr, nullptr);
  scan_agg_kernel<<<2 * CH * PP / 256, 256, 0, stream>>>(Ler, Lei, P,
                                                         aggAr, aggAi, aggBr, aggBi);
  scan_carry_kernel<<<4, 256, 0, stream>>>(aggAr, aggAi, aggBr, aggBi, carR, carI);
  scan_apply_kernel<<<2 * CH * PP / 256, 256, 0, stream>>>(Ler, Lei, P, carR, carI, A2);
  gemm_k<1, false><<<1024, 256, 0, stream>>>(A2, (const u16*)B2, 2048, Y, Dv, U);
}

// Round 9
// 123.925 us; speedup vs baseline: 2.1202x; 1.0887x over previous
//
#include <hip/hip_runtime.h>

#define LL 4096
#define HH 1024
#define PP 512
#define RR 16
#define CH 128   // scan chunks
#define CL 32    // steps per chunk

typedef _Float16 f16x8 __attribute__((ext_vector_type(8)));
typedef float f32x4 __attribute__((ext_vector_type(4)));
typedef unsigned short u16;
typedef unsigned int u32;

#define MF16(a, b, c) __builtin_amdgcn_mfma_f32_16x16x32_f16(a, b, c, 0, 0, 0)

__device__ __forceinline__ u16 h16(float x) {
  _Float16 h = (_Float16)x;
  return __builtin_bit_cast(u16, h);
}
__device__ __forceinline__ float f16f(u16 v) {
  return (float)__builtin_bit_cast(_Float16, v);
}

// ---------------------------------------------------------------- precompute
__global__ void precompute_kernel(const float* __restrict__ Lre, const float* __restrict__ Lim,
                                  const float* __restrict__ lst,
                                  const float* __restrict__ Ere, const float* __restrict__ Eim,
                                  const float* __restrict__ Fre, const float* __restrict__ Fim,
                                  float* __restrict__ Lbr, float* __restrict__ Lbi,
                                  float* __restrict__ cfr, float* __restrict__ cfi,
                                  float* __restrict__ EFr, float* __restrict__ EFi)
{
  int p = blockIdx.x * blockDim.x + threadIdx.x;
  if (p >= PP) return;
  float lre = fminf(Lre[p], -1e-4f);   // clip_eigs
  float lim = Lim[p];
  float st  = expf(lst[p]);
  float er  = expf(lre * st);
  float s, c;
  sincosf(lim * st, &s, &c);
  float lbr = er * c, lbi = er * s;    // Lambda_bar
  Lbr[p] = lbr; Lbi[p] = lbi;
  float den = lre * lre + lim * lim;
  float nr  = lbr - 1.0f;
  cfr[p] = (nr * lre + lbi * lim) / den;
  cfi[p] = (lbi * lre - nr * lim) / den;
  for (int r = 0; r < RR; ++r) {
    float e_r = Ere[p * RR + r], e_i = Eim[p * RR + r];
    float f_r = Fre[r * PP + p], f_i = Fim[r * PP + p];
    EFr[r * PP + p] = e_r * f_r - e_i * f_i;
    EFi[r * PP + p] = e_r * f_i + e_i * f_r;
  }
}

// ---------------------------------------------------------------- B_bar -> B1 fp16 [1024][1024]
__global__ void bbar_kernel(const float* __restrict__ Bre, const float* __restrict__ Bim,
                            const float* __restrict__ cfr, const float* __restrict__ cfi,
                            u16* __restrict__ B1)
{
  int i = blockIdx.x * blockDim.x + threadIdx.x;
  int base = i * 4;
  if (base >= PP * HH) return;
  int p = base >> 10, col = base & 1023;
  float cr = cfr[p], ci = cfi[p];
  float4 br = *(const float4*)&Bre[base];
  float4 bi = *(const float4*)&Bim[base];
  ushort4 rp, ip;
  rp.x = h16(cr*br.x - ci*bi.x); ip.x = h16(cr*bi.x + ci*br.x);
  rp.y = h16(cr*br.y - ci*bi.y); ip.y = h16(cr*bi.y + ci*br.y);
  rp.z = h16(cr*br.z - ci*bi.z); ip.z = h16(cr*bi.z + ci*br.z);
  rp.w = h16(cr*br.w - ci*bi.w); ip.w = h16(cr*bi.w + ci*br.w);
  *(ushort4*)&B1[(size_t)p * 1024 + col] = rp;
  *(ushort4*)&B1[(size_t)(PP + p) * 1024 + col] = ip;
}

// ---------------------------------------------------------------- C -> B2 interleaved (cr,-ci)
__global__ void prep_c_kernel(const float* __restrict__ Cre, const float* __restrict__ Cim,
                              u32* __restrict__ B2)
{
  int i = blockIdx.x * blockDim.x + threadIdx.x;
  int base = i * 4;
  float4 a = *(const float4*)&Cre[base];
  float4 b = *(const float4*)&Cim[base];
  uint4 o;
  o.x = (u32)h16(a.x) | ((u32)h16(-b.x) << 16);
  o.y = (u32)h16(a.y) | ((u32)h16(-b.y) << 16);
  o.z = (u32)h16(a.z) | ((u32)h16(-b.z) << 16);
  o.w = (u32)h16(a.w) | ((u32)h16(-b.w) << 16);
  *(uint4*)&B2[base] = o;
}

// ---------------------------------------------------------------- ext = Dt@EF, packed fp16 pairs
__global__ __launch_bounds__(256) void ext_kernel(
    const float* __restrict__ Dt, const float* __restrict__ EFr, const float* __restrict__ EFi,
    u32* __restrict__ LE)
{
  int gid = blockIdx.x * 256 + threadIdx.x;
  int l  = gid >> 7;
  int pq = (gid & 127) << 2;
  float4 ar = {0.f, 0.f, 0.f, 0.f};
  float4 ai = {0.f, 0.f, 0.f, 0.f};
#pragma unroll
  for (int r = 0; r < RR; ++r) {
    float d = Dt[l * RR + r];
    float4 er = *(const float4*)&EFr[r * PP + pq];
    float4 ei = *(const float4*)&EFi[r * PP + pq];
    ar.x = fmaf(d, er.x, ar.x); ar.y = fmaf(d, er.y, ar.y);
    ar.z = fmaf(d, er.z, ar.z); ar.w = fmaf(d, er.w, ar.w);
    ai.x = fmaf(d, ei.x, ai.x); ai.y = fmaf(d, ei.y, ai.y);
    ai.z = fmaf(d, ei.z, ai.z); ai.w = fmaf(d, ei.w, ai.w);
  }
  uint4 o;
  o.x = (u32)h16(ar.x) | ((u32)h16(ai.x) << 16);
  o.y = (u32)h16(ar.y) | ((u32)h16(ai.y) << 16);
  o.z = (u32)h16(ar.z) | ((u32)h16(ai.z) << 16);
  o.w = (u32)h16(ar.w) | ((u32)h16(ai.w) << 16);
  *(uint4*)&LE[(size_t)l * PP + pq] = o;
}

// ---------------------------------------------------------------- unified GEMM
// out[M][1024] = A[M][Kp] @ B[1024][Kp]^T, fp16 operands, fp32 acc.
// 64x64 tile, 4 waves 2x2 (32x32), 16x16x32 MFMA, BK=64, 2-deep prefetch.
// grid = 16 n-tiles * (M/64); n-tile = (bid&7)*2 + ((bid>>3)&1) -> XCD-resident B panel.
// LDS: 2 buf x (A 8 segs + B 8 segs) x 1KB. Fragment(row,kq) 16B at
// slot (kq&3)*16 + ((row&15)^(2*(kq&3))) -> conflict-free reads AND writes.
template<int EPI, bool ACVT>
__global__ __launch_bounds__(256) void gemm_k(
    const void* __restrict__ Asrc, const u16* __restrict__ Bsrc, int Kp,
    float* __restrict__ out, const float* __restrict__ Dv,
    const float* __restrict__ Uep)
{
  __shared__ __align__(16) uint4 lds[2 * 16 * 64];   // 32 KB
  int bid = blockIdx.x;
  int n0 = ((bid & 7) * 2 + ((bid >> 3) & 1)) * 64;  // 16 n-tiles = 1024 cols
  int m0 = (bid >> 4) * 64;
  int t = threadIdx.x, lane = t & 63, w = t >> 6;
  int wr = w >> 1, wc = w & 1;
  int rl = lane & 15, kg = lane >> 4;
  int crow = t >> 2, cch = t & 3;
  int NT = Kp / 64;

  const float* Af = (const float*)Asrc;
  const u16*   Ah = (const u16*)Asrc;

  f32x4 acc[2][2];
  acc[0][0] = acc[0][1] = acc[1][0] = acc[1][1] = (f32x4){0.f, 0.f, 0.f, 0.f};

  struct Frags { uint4 a[2]; uint4 b[2]; };
  auto LOAD = [&](int kt) -> Frags {
    Frags f;
    if constexpr (ACVT) {
      const float* p = Af + (size_t)(m0 + crow) * Kp + kt * 64 + cch * 16;
#pragma unroll
      for (int j = 0; j < 2; ++j) {
        float4 a = *(const float4*)(p + j * 8), b = *(const float4*)(p + j * 8 + 4);
        f16x8 r;
        r[0] = (_Float16)a.x; r[1] = (_Float16)a.y; r[2] = (_Float16)a.z; r[3] = (_Float16)a.w;
        r[4] = (_Float16)b.x; r[5] = (_Float16)b.y; r[6] = (_Float16)b.z; r[7] = (_Float16)b.w;
        f.a[j] = __builtin_bit_cast(uint4, r);
      }
    } else {
      const u16* p = Ah + (size_t)(m0 + crow) * Kp + kt * 64 + cch * 16;
      f.a[0] = *(const uint4*)p;
      f.a[1] = *(const uint4*)(p + 8);
    }
    const u16* q = Bsrc + (size_t)(n0 + crow) * Kp + kt * 64 + cch * 16;
    f.b[0] = *(const uint4*)q;
    f.b[1] = *(const uint4*)(q + 8);
    return f;
  };
  auto WRITE = [&](int buf, const Frags& f) {
#pragma unroll
    for (int j = 0; j < 2; ++j) {
      int kq = cch * 2 + j;
      int c = kq & 3;
      int slot = c * 16 + ((crow & 15) ^ (c * 2));
      int segA = (crow >> 4) * 2 + (kq >> 2);
      lds[buf * 1024 + segA * 64 + slot] = f.a[j];
      lds[buf * 1024 + (8 + segA) * 64 + slot] = f.b[j];
    }
  };

  Frags nxt, far;
  WRITE(0, LOAD(0));
  nxt = LOAD(1);
  __syncthreads();

  for (int kt = 0; kt < NT; ++kt) {
    int c = kt & 1;
    if (kt + 2 < NT) far = LOAD(kt + 2);
    int rslot = kg * 16 + (rl ^ (kg * 2));
    f16x8 af[2][2], bf[2][2];
#pragma unroll
    for (int m = 0; m < 2; ++m)
#pragma unroll
      for (int ks = 0; ks < 2; ++ks) {
        int segA = (wr * 2 + m) * 2 + ks;
        int segB = 8 + (wc * 2 + m) * 2 + ks;
        af[m][ks] = __builtin_bit_cast(f16x8, lds[c * 1024 + segA * 64 + rslot]);
        bf[m][ks] = __builtin_bit_cast(f16x8, lds[c * 1024 + segB * 64 + rslot]);
      }
#pragma unroll
    for (int ks = 0; ks < 2; ++ks)
#pragma unroll
      for (int m = 0; m < 2; ++m)
#pragma unroll
        for (int n = 0; n < 2; ++n)
          acc[m][n] = MF16(af[m][ks], bf[n][ks], acc[m][n]);
    if (kt + 1 < NT) WRITE(c ^ 1, nxt);
    nxt = far;
    __syncthreads();
  }

  // epilogue: stage in LDS (reuse), float4 stores
  float* Stg = (float*)lds;   // [64][68]
#pragma unroll
  for (int m = 0; m < 2; ++m)
#pragma unroll
    for (int n = 0; n < 2; ++n)
#pragma unroll
      for (int j = 0; j < 4; ++j)
        Stg[(wr * 32 + m * 16 + kg * 4 + j) * 68 + wc * 32 + n * 16 + rl] = acc[m][n][j];
  __syncthreads();
  int col4 = (t & 15) * 4, prow = t >> 4;
#pragma unroll
  for (int i = 0; i < 4; ++i) {
    int r = prow + 16 * i;
    float4 v = *(const float4*)&Stg[r * 68 + col4];
    size_t ob = (size_t)(m0 + r) * 1024 + n0 + col4;
    if constexpr (EPI == 1) {
      float4 u4 = *(const float4*)&Uep[ob];
      float4 dv = *(const float4*)&Dv[n0 + col4];
      v.x = 2.f * v.x + dv.x * u4.x; v.y = 2.f * v.y + dv.y * u4.y;
      v.z = 2.f * v.z + dv.z * u4.z; v.w = 2.f * v.w + dv.w * u4.w;
    }
    *(float4*)&out[ob] = v;
  }
}

// ---------------------------------------------------------------- scan phase 1
// A[l][p] = (Lbr[p],Lbi[p]) + unpack(LE[l*512+p]); b from P (re p, im 512+p)
__global__ __launch_bounds__(256) void scan_agg_kernel(
    const float* __restrict__ Lbr, const float* __restrict__ Lbi,
    const u32* __restrict__ LE, const float* __restrict__ P,
    float* __restrict__ aggAr, float* __restrict__ aggAi,
    float* __restrict__ aggBr, float* __restrict__ aggBi)
{
  int tid = blockIdx.x * 256 + threadIdx.x;
  int p   = tid & (PP - 1);
  int c   = (tid >> 9) & (CH - 1);
  int dir = tid >> 16;
  float lbr = Lbr[p], lbi = Lbi[p];
  float Ar = 1.f, Ai = 0.f, br = 0.f, bi = 0.f;
  int base = c * CL;
#pragma unroll
  for (int g = 0; g < CL / 8; ++g) {
    float ar8[8], ai8[8], br8[8], bi8[8];
#pragma unroll
    for (int u = 0; u < 8; ++u) {
      int l = base + g * 8 + u;
      int phys = dir ? (LL - 1 - l) : l;
      u32 v = LE[(size_t)phys * PP + p];
      ar8[u] = lbr + f16f((u16)(v & 0xffff));
      ai8[u] = lbi + f16f((u16)(v >> 16));
      br8[u] = P[(size_t)phys * 1024 + p];
      bi8[u] = P[(size_t)phys * 1024 + PP + p];
    }
#pragma unroll
    for (int u = 0; u < 8; ++u) {
      float nAr = ar8[u] * Ar - ai8[u] * Ai;
      float nAi = ar8[u] * Ai + ai8[u] * Ar;
      float nbr = fmaf(ar8[u], br, fmaf(-ai8[u], bi, br8[u]));
      float nbi = fmaf(ar8[u], bi, fmaf( ai8[u], br, bi8[u]));
      Ar = nAr; Ai = nAi; br = nbr; bi = nbi;
    }
  }
  aggAr[tid] = Ar; aggAi[tid] = Ai; aggBr[tid] = br; aggBi[tid] = bi;
}

// ---------------------------------------------------------------- scan phase 2
__global__ __launch_bounds__(256) void scan_carry_kernel(
    const float* __restrict__ aggAr, const float* __restrict__ aggAi,
    const float* __restrict__ aggBr, const float* __restrict__ aggBi,
    float* __restrict__ carR, float* __restrict__ carI)
{
  int tid = blockIdx.x * 256 + threadIdx.x;
  int p   = tid & (PP - 1);
  int dir = tid >> 9;
  float xr = 0.f, xi = 0.f;
  for (int c = 0; c < CH; ++c) {
    int idx = (dir * CH + c) * PP + p;
    carR[idx] = xr; carI[idx] = xi;
    float ar = aggAr[idx], ai = aggAi[idx];
    float br = aggBr[idx], bi = aggBi[idx];
    float nr = fmaf(ar, xr, fmaf(-ai, xi, br));
    float ni = fmaf(ar, xi, fmaf( ai, xr, bi));
    xr = nr; xi = ni;
  }
}

// ---------------------------------------------------------------- scan phase 3
// writes A2[l][k] = (h16(im)<<16)|h16(re), k = dir*512+p
__global__ __launch_bounds__(256) void scan_apply_kernel(
    const float* __restrict__ Lbr, const float* __restrict__ Lbi,
    const u32* __restrict__ LE, const float* __restrict__ P,
    const float* __restrict__ carR, const float* __restrict__ carI,
    u32* __restrict__ A2)
{
  int tid = blockIdx.x * 256 + threadIdx.x;
  int p   = tid & (PP - 1);
  int c   = (tid >> 9) & (CH - 1);
  int dir = tid >> 16;
  float lbr = Lbr[p], lbi = Lbi[p];
  float xr = carR[tid], xi = carI[tid];
  int base = c * CL;
  int cofs = dir * PP + p;
#pragma unroll
  for (int g = 0; g < CL / 8; ++g) {
    float ar8[8], ai8[8], br8[8], bi8[8];
#pragma unroll
    for (int u = 0; u < 8; ++u) {
      int l = base + g * 8 + u;
      int phys = dir ? (LL - 1 - l) : l;
      u32 v = LE[(size_t)phys * PP + p];
      ar8[u] = lbr + f16f((u16)(v & 0xffff));
      ai8[u] = lbi + f16f((u16)(v >> 16));
      br8[u] = P[(size_t)phys * 1024 + p];
      bi8[u] = P[(size_t)phys * 1024 + PP + p];
    }
#pragma unroll
    for (int u = 0; u < 8; ++u) {
      float nr = fmaf(ar8[u], xr, fmaf(-ai8[u], xi, br8[u]));
      float ni = fmaf(ar8[u], xi, fmaf( ai8[u], xr, bi8[u]));
      xr = nr; xi = ni;
      int l = base + g * 8 + u;
      int phys = dir ? (LL - 1 - l) : l;
      A2[(size_t)phys * 1024 + cofs] = (u32)h16(xr) | ((u32)h16(xi) << 16);
    }
  }
}

// ---------------------------------------------------------------- launch
extern "C" void kernel_launch(void* const* d_in, const int* in_sizes, int n_in,
                              void* d_out, int out_size, void* d_ws, size_t ws_size,
                              hipStream_t stream)
{
  const float* U   = (const float*)d_in[0];
  const float* Lre = (const float*)d_in[1];
  const float* Lim = (const float*)d_in[2];
  const float* Bre = (const float*)d_in[3];
  const float* Bim = (const float*)d_in[4];
  const float* Cre = (const float*)d_in[5];
  const float* Cim = (const float*)d_in[6];
  const float* Ere = (const float*)d_in[7];
  const float* Eim = (const float*)d_in[8];
  const float* Fre = (const float*)d_in[9];
  const float* Fim = (const float*)d_in[10];
  const float* Dv  = (const float*)d_in[11];
  const float* lst = (const float*)d_in[12];
  const float* Dt  = (const float*)d_in[13];
  float* Y = (float*)d_out;

  char* wsb = (char*)d_ws;
  size_t o = 0;
  auto alloc = [&](size_t bytes) -> char* {
    char* r = wsb + o; o += (bytes + 255) & ~(size_t)255; return r;
  };
  float* Lbr = (float*)alloc(PP * 4);
  float* Lbi = (float*)alloc(PP * 4);
  float* cfr = (float*)alloc(PP * 4);
  float* cfi = (float*)alloc(PP * 4);
  float* EFr = (float*)alloc((size_t)RR * PP * 4);
  float* EFi = (float*)alloc((size_t)RR * PP * 4);
  u16* B1 = (u16*)alloc((size_t)1024 * 1024 * 2);        // [p|512+p][k] re|im B_bar
  u32* B2 = (u32*)alloc((size_t)1024 * 1024 * 4);        // C interleaved (cr,-ci)
  u32* LE = (u32*)alloc((size_t)LL * PP * 4);            // ext packed fp16 pairs
  float* P = (float*)alloc((size_t)LL * 1024 * 4);       // [Bur | Bui]
  u32* A2 = (u32*)alloc((size_t)LL * 1024 * 4);          // xs interleaved
  const int NAGG = 2 * CH * PP;                          // 131072
  float* aggAr = (float*)alloc((size_t)NAGG * 4);
  float* aggAi = (float*)alloc((size_t)NAGG * 4);
  float* aggBr = (float*)alloc((size_t)NAGG * 4);
  float* aggBi = (float*)alloc((size_t)NAGG * 4);
  float* carR  = (float*)alloc((size_t)NAGG * 4);
  float* carI  = (float*)alloc((size_t)NAGG * 4);

  precompute_kernel<<<2, 256, 0, stream>>>(Lre, Lim, lst, Ere, Eim, Fre, Fim,
                                           Lbr, Lbi, cfr, cfi, EFr, EFi);
  bbar_kernel<<<PP * HH / 4 / 256, 256, 0, stream>>>(Bre, Bim, cfr, cfi, B1);
  prep_c_kernel<<<1024 * 1024 / 4 / 256, 256, 0, stream>>>(Cre, Cim, B2);
  ext_kernel<<<LL * PP / 4 / 256, 256, 0, stream>>>(Dt, EFr, EFi, LE);
  gemm_k<0, true><<<1024, 256, 0, stream>>>(U, B1, 1024, P, nullptr, nullptr);
  scan_agg_kernel<<<2 * CH * PP / 256, 256, 0, stream>>>(Lbr, Lbi, LE, P,
                                                         aggAr, aggAi, aggBr, aggBi);
  scan_carry_kernel<<<4, 256, 0, stream>>>(aggAr, aggAi, aggBr, aggBi, carR, carI);
  scan_apply_kernel<<<2 * CH * PP / 256, 256, 0, stream>>>(Lbr, Lbi, LE, P, carR, carI, A2);
  gemm_k<1, false><<<1024, 256, 0, stream>>>(A2, (const u16*)B2, 2048, Y, Dv, U);
}